// Round 13
// baseline (139.769 us; speedup 1.0000x reference)
//
#include <hip/hip_runtime.h>

#define NPTS 1000000
#define FDIM 64
#define CNUM 128
#define PSTRIDE 8320          // f16 elements: 8192 sums (f-major [f*128+c]) + 128 counts
#define NB1 1536              // k1 grid
#define NB3 1536              // k3 grid: 6 blocks/CU

typedef _Float16 half8 __attribute__((ext_vector_type(8)));
typedef _Float16 half4v __attribute__((ext_vector_type(4)));
typedef float f32x4 __attribute__((ext_vector_type(4)));

// ---------------- K1: cluster sums via MFMA (onehot^T x X), f-half split ----------
// Round-10 proven structure (best: 131us). Wave-pair shares a tile stream; wave
// handles f in [fh*32,+32). acc[8][2] = 64 AGPR (+~60 VGPR -> 4 waves/SIMD cap).
// Partials now f16 (halved write traffic), NONTEMPORAL (no L3 pollution).
__global__ __launch_bounds__(256, 4) void k1_partials(
    const float* __restrict__ feats, const int* __restrict__ labels,
    _Float16* __restrict__ partials, int nblocks)
{
    __shared__ _Float16 ldsH[FDIM * 132];  // [f][c] padded to 132 (f16)
    __shared__ float cnt[CNUM];
    const int tid = threadIdx.x;
    if (tid < CNUM) cnt[tid] = 0.f;
    __syncthreads();

    const int lane = tid & 63;
    const int n15 = lane & 15;
    const int kb = (lane >> 4) * 8;        // k-slot base
    const int rowb = (lane >> 4) * 4;      // C/D row base
    const int w = tid >> 6;
    const int fh = w & 1;                  // feature half
    const int fbase = fh * 32;
    const int nstreams = nblocks * 2;
    const int ts = ((blockIdx.x << 2) + w) >> 1;   // tile stream id

    f32x4 acc[8][2];
    #pragma unroll
    for (int ct = 0; ct < 8; ++ct)
        #pragma unroll
        for (int nt = 0; nt < 2; ++nt)
            acc[ct][nt] = (f32x4){0.f, 0.f, 0.f, 0.f};

    const int ntiles = NPTS / 32;          // 31250
    for (int t = ts; t < ntiles; t += nstreams) {
        const int p0 = t * 32;
        const float* fp = feats + (size_t)(p0 + kb) * FDIM + fbase + n15;
        // labels via 4 x int4 (ids at odd slots); addr 16B-aligned (p0+kb even)
        const int4* lq = (const int4*)(labels + 2 * (p0 + kb));
        int vlab[8];
        {
            int4 a0 = lq[0], a1 = lq[1], a2 = lq[2], a3 = lq[3];
            vlab[0] = a0.y; vlab[1] = a0.w; vlab[2] = a1.y; vlab[3] = a1.w;
            vlab[4] = a2.y; vlab[5] = a2.w; vlab[6] = a3.y; vlab[7] = a3.w;
        }

        half8 B[2];
        #pragma unroll
        for (int nt = 0; nt < 2; ++nt) {
            #pragma unroll
            for (int i = 0; i < 8; ++i)
                B[nt][i] = (_Float16)fp[i * FDIM + nt * 16];
        }
        // counts: fh==0 waves only, one lane-op per point
        if (fh == 0 && lane < 32) {
            const int myl = labels[2 * (p0 + lane) + 1];
            atomicAdd(&cnt[myl], 1.0f);
        }
        #pragma unroll
        for (int ct = 0; ct < 8; ++ct) {
            const int cmine = ct * 16 + n15;
            union { unsigned u[4]; half8 h; } ua;
            #pragma unroll
            for (int j = 0; j < 4; ++j)
                ua.u[j] = ((vlab[2 * j] == cmine) ? 0x3C00u : 0u)
                        | ((vlab[2 * j + 1] == cmine) ? 0x3C000000u : 0u);
            #pragma unroll
            for (int nt = 0; nt < 2; ++nt)
                acc[ct][nt] = __builtin_amdgcn_mfma_f32_16x16x32_f16(
                    ua.h, B[nt], acc[ct][nt], 0, 0, 0);
        }
    }
    __syncthreads();

    // 2-round merge into f16 LDS: waves 0,1 write (disjoint f-halves); 2,3 add.
    for (int r = 0; r < 2; ++r) {
        if ((w >> 1) == r) {
            #pragma unroll
            for (int ct = 0; ct < 8; ++ct)
                #pragma unroll
                for (int nt = 0; nt < 2; ++nt) {
                    _Float16* a = &ldsH[(fbase + nt * 16 + n15) * 132 + ct * 16 + rowb];
                    half4v h;
                    if (r == 0) {
                        #pragma unroll
                        for (int q = 0; q < 4; ++q) h[q] = (_Float16)acc[ct][nt][q];
                    } else {
                        half4v o = *(const half4v*)a;
                        #pragma unroll
                        for (int q = 0; q < 4; ++q)
                            h[q] = (_Float16)((float)o[q] + acc[ct][nt][q]);
                    }
                    *(half4v*)a = h;
                }
        }
        __syncthreads();
    }

    // nontemporal f16 writeout (half traffic of round 10)
    _Float16* dst = partials + (size_t)blockIdx.x * PSTRIDE;
    for (int i8 = tid; i8 < 1040; i8 += 256) {        // half8 units
        half8 v;
        if (i8 < 1024) {
            const int f = i8 >> 4, c0 = (i8 & 15) * 8;
            v = *(const half8*)&ldsH[f * 132 + c0];
        } else {
            const int c0 = (i8 - 1024) * 8;
            #pragma unroll
            for (int q = 0; q < 8; ++q) v[q] = (_Float16)cnt[c0 + q];
        }
        __builtin_nontemporal_store(v, (half8*)dst + i8);
    }
}

// ---------------- K2: reduce f16 partials -> red f32 (nontemporal reads) --------
// red[0..8191] c-major [c*64+f]; red[8192..8319] counts.
__global__ __launch_bounds__(256) void k2_reduce(
    const _Float16* __restrict__ partials, int nblocks, float* __restrict__ red,
    float* __restrict__ ppsum, float* __restrict__ dsum, int* __restrict__ counter)
{
    const int tid = threadIdx.x;
    const int tsub = tid & 31, grp = tid >> 5;
    const int t0 = blockIdx.x * 32;                 // 260 blocks cover 8320
    float s = 0.f;
    #pragma unroll 8
    for (int b = grp; b < nblocks; b += 8)
        s += (float)__builtin_nontemporal_load(
                 &partials[(size_t)b * PSTRIDE + t0 + tsub]);
    __shared__ float lred[8][33];
    lred[grp][tsub] = s;
    __syncthreads();
    if (tid < 32) {
        float tot = 0.f;
        #pragma unroll
        for (int q = 0; q < 8; ++q) tot += lred[q][tid];
        const int t = t0 + tid;
        if (t < 8192) red[(t & 127) * FDIM + (t >> 7)] = tot;  // f-major -> c-major
        else red[t] = tot;
    }
    if (blockIdx.x == 0) {
        if (tid >= 128) ppsum[tid - 128] = 0.f;
        if (tid == 64) dsum[0] = 0.f;
        if (tid == 65) counter[0] = 0;
    }
}

// ---------------- K3: variance term (REVERSE traversal, 24 waves/CU) -------------
__global__ __launch_bounds__(256, 6) void k3_var(
    const float4* __restrict__ feats4, const int* __restrict__ labels,
    const float* __restrict__ red, float* __restrict__ ppsum, int nblocks)
{
    __shared__ float4 mu4[CNUM * 16];   // [c][16] (quarter-wave shares c: no pad)
    __shared__ float lpp[CNUM];
    const int tid = threadIdx.x;
    for (int i = tid; i < 2048; i += 256) {
        float4 sv = ((const float4*)red)[i];
        float ci = 1.0f / red[8192 + (i >> 4)];
        mu4[i] = make_float4(sv.x * ci, sv.y * ci, sv.z * ci, sv.w * ci);
    }
    if (tid < CNUM) lpp[tid] = 0.f;
    __syncthreads();

    const int lane = tid & 63;
    const int k = lane & 15, g = lane >> 4;
    const int nwaves = nblocks * 4;
    const int wid = ((blockIdx.x << 8) + tid) >> 6;
    const int ntiles = NPTS / 16;           // 62500 tiles of 16 points

    // reverse: start at the tail (most recently L3-cached by k1), walk backward
    int b = ntiles - 1 - wid;
    float4 v[4]; int cc = 0;
    if (b >= 0) {
        const float4* fp = feats4 + (size_t)b * 256 + lane;
        #pragma unroll
        for (int s = 0; s < 4; ++s) v[s] = fp[s * 64];
        cc = labels[2 * (b * 16 + k) + 1];
    }
    while (b >= 0) {
        const int bn = b - nwaves;
        float4 vn[4]; int ccn = 0;
        if (bn >= 0) {
            const float4* fp = feats4 + (size_t)bn * 256 + lane;
            #pragma unroll
            for (int s = 0; s < 4; ++s) vn[s] = fp[s * 64];
            ccn = labels[2 * (bn * 16 + k) + 1];
        }
        #pragma unroll
        for (int s = 0; s < 4; ++s) {
            const int c = __shfl(cc, 4 * s + g);
            float4 m = mu4[c * 16 + k];
            float dx = v[s].x - m.x, dy = v[s].y - m.y,
                  dz = v[s].z - m.z, dw = v[s].w - m.w;
            float sq = dx * dx + dy * dy + dz * dz + dw * dw;
            sq += __shfl_xor(sq, 1); sq += __shfl_xor(sq, 2);
            sq += __shfl_xor(sq, 4); sq += __shfl_xor(sq, 8);
            if (k == 0) {
                const float t = sqrtf(sq) - 0.5f;      // DELTA_VAR
                if (t > 0.f) atomicAdd(&lpp[c], t * t);
            }
        }
        b = bn;
        #pragma unroll
        for (int s = 0; s < 4; ++s) v[s] = vn[s];
        cc = ccn;
    }
    __syncthreads();
    if (tid < CNUM) atomicAdd(&ppsum[tid], lpp[tid]);
}

// ---------------- K45: pairwise dist loss + last-block finalize ----------------
__global__ __launch_bounds__(128) void k45_dist_final(
    const float* __restrict__ red, const float* __restrict__ ppsum,
    float* __restrict__ dsum, int* __restrict__ counter, float* __restrict__ out)
{
    __shared__ float4 mu4[CNUM * 17];   // padded: lanes read different rows
    __shared__ int lastflag;
    __shared__ float sv[2];
    const int tid = threadIdx.x;
    for (int i = tid; i < 2048; i += 128) {
        float4 s4 = ((const float4*)red)[i];
        float ci = 1.0f / red[8192 + (i >> 4)];
        mu4[(i >> 4) * 17 + (i & 15)] =
            make_float4(s4.x * ci, s4.y * ci, s4.z * ci, s4.w * ci);
    }
    __syncthreads();
    const int i = blockIdx.x, j = tid;
    float sq = 0.f;
    #pragma unroll
    for (int q = 0; q < 16; ++q) {
        float4 a = mu4[i * 17 + q], b = mu4[j * 17 + q];
        float dx = a.x - b.x, dy = a.y - b.y, dz = a.z - b.z, dw = a.w - b.w;
        sq += dx * dx + dy * dy + dz * dz + dw * dw;
    }
    float dl = 0.f;
    if (j != i) {
        const float r = 3.0f - sqrtf(sq);   // DELTA_DIST
        if (r > 0.f) dl = r * r;
    }
    #pragma unroll
    for (int m = 1; m < 64; m <<= 1) dl += __shfl_xor(dl, m);
    if ((tid & 63) == 0) atomicAdd(dsum, dl);
    __threadfence();
    __syncthreads();
    if (tid == 0) lastflag = (atomicAdd(counter, 1) == (int)gridDim.x - 1);
    __syncthreads();
    if (lastflag) {
        float v = ppsum[tid] / red[8192 + tid];
        #pragma unroll
        for (int m = 1; m < 64; m <<= 1) v += __shfl_xor(v, m);
        if ((tid & 63) == 0) sv[tid >> 6] = v;
    }
    __syncthreads();
    if (lastflag && tid == 0) {
        const float dtot = atomicAdd(dsum, 0.0f);   // device-scope read
        out[0] = (sv[0] + sv[1]) / (float)CNUM
               + dtot / (float)(CNUM * (CNUM - 1));
    }
}

extern "C" void kernel_launch(void* const* d_in, const int* in_sizes, int n_in,
                              void* d_out, int out_size, void* d_ws, size_t ws_size,
                              hipStream_t stream) {
    (void)in_sizes; (void)n_in; (void)out_size;
    const float* feats   = (const float*)d_in[0];
    const float4* feats4 = (const float4*)d_in[0];
    const int* labels    = (const int*)d_in[1];
    float* out           = (float*)d_out;

    int nb1 = NB1;
    {
        const size_t tail = (size_t)(PSTRIDE + 130) * 4;     // red + ppsum + dsum + counter
        if (ws_size > tail) {
            size_t cap = (ws_size - tail) / ((size_t)PSTRIDE * sizeof(_Float16));
            if ((size_t)nb1 > cap) nb1 = (int)cap;
        } else nb1 = 1;
        if (nb1 < 1) nb1 = 1;
    }
    _Float16* partials = (_Float16*)d_ws;
    float* red      = (float*)((char*)d_ws + (size_t)nb1 * PSTRIDE * 2);  // 16B-aligned
    float* ppsum    = red + PSTRIDE;
    float* dsum     = ppsum + 128;
    int*   counter  = (int*)(dsum + 1);

    k1_partials<<<nb1, 256, 0, stream>>>(feats, labels, partials, nb1);
    k2_reduce<<<PSTRIDE / 32, 256, 0, stream>>>(partials, nb1, red, ppsum, dsum, counter);
    k3_var<<<NB3, 256, 0, stream>>>(feats4, labels, red, ppsum, NB3);
    k45_dist_final<<<CNUM, 128, 0, stream>>>(red, ppsum, dsum, counter, out);
}